// Round 1
// baseline (171.203 us; speedup 1.0000x reference)
//
#include <hip/hip_runtime.h>

// Problem constants (from reference setup_inputs)
#define NBOX 256
#define NC   32
#define ND   64
#define NH   64
#define NW   64
#define CD   16
#define CH   16
#define CW   16

__global__ __launch_bounds__(256) void CropAndResize3D_89481348645400_kernel(
    const float* __restrict__ image,   // (N, C, D, H, W)
    const float* __restrict__ boxes,   // (NB, 6) = x1,y1,z1,x2,y2,z2
    const int*   __restrict__ box_ind, // (NB,)
    float*       __restrict__ out)     // (NB, C, CD, CH, CW)
{
    const int blk = blockIdx.x;       // NBOX * CD blocks
    const int b = blk >> 4;           // box index
    const int z = blk & 15;           // crop depth index
    const int t = threadIdx.x;        // 256 threads = 16x16 (y,x)
    const int y = t >> 4;
    const int x = t & 15;

    // boxes layout: [x1, y1, z1, x2, y2, z2]
    const float bx1 = boxes[b * 6 + 0];
    const float by1 = boxes[b * 6 + 1];
    const float bz1 = boxes[b * 6 + 2];
    const float bx2 = boxes[b * 6 + 3];
    const float by2 = boxes[b * 6 + 4];
    const float bz2 = boxes[b * 6 + 5];
    const int   n   = box_ind[b];

    // coords exactly as reference: lo*(L-1) + i * ((hi-lo)*(L-1)/(c-1))
    const float zstep = (bz2 - bz1) * (float)(ND - 1) / (float)(CD - 1);
    const float ystep = (by2 - by1) * (float)(NH - 1) / (float)(CH - 1);
    const float xstep = (bx2 - bx1) * (float)(NW - 1) / (float)(CW - 1);
    const float zc = bz1 * (float)(ND - 1) + (float)z * zstep;
    const float yc = by1 * (float)(NH - 1) + (float)y * ystep;
    const float xc = bx1 * (float)(NW - 1) + (float)x * xstep;

    const bool valid =
        (zc >= 0.0f) && (zc <= (float)(ND - 1)) &&
        (yc >= 0.0f) && (yc <= (float)(NH - 1)) &&
        (xc >= 0.0f) && (xc <= (float)(NW - 1));

    // clamp + split into integer corners and fractions
    const float zq = fminf(fmaxf(zc, 0.0f), (float)(ND - 1));
    const float yq = fminf(fmaxf(yc, 0.0f), (float)(NH - 1));
    const float xq = fminf(fmaxf(xc, 0.0f), (float)(NW - 1));
    const int z0 = (int)floorf(zq);
    const int y0 = (int)floorf(yq);
    const int x0 = (int)floorf(xq);
    const int z1 = min(z0 + 1, ND - 1);
    const int y1 = min(y0 + 1, NH - 1);
    const int x1 = min(x0 + 1, NW - 1);
    const float fz = zq - (float)z0;
    const float fy = yq - (float)y0;
    const float fx = xq - (float)x0;
    const float gz = 1.0f - fz, gy = 1.0f - fy, gx = 1.0f - fx;

    // 8 trilinear weights (channel-invariant)
    const float w000 = gz * gy * gx, w001 = gz * gy * fx;
    const float w010 = gz * fy * gx, w011 = gz * fy * fx;
    const float w100 = fz * gy * gx, w101 = fz * gy * fx;
    const float w110 = fz * fy * gx, w111 = fz * fy * fx;

    // channel-invariant spatial offsets within a (D,H,W) volume
    const int o00 = (z0 * NH + y0) * NW;
    const int o01 = (z0 * NH + y1) * NW;
    const int o10 = (z1 * NH + y0) * NW;
    const int o11 = (z1 * NH + y1) * NW;

    const float* img = image + (size_t)n * (NC * ND * NH * NW);
    float* op = out + (size_t)b * (NC * CD * CH * CW) + (z * CH + y) * CW + x;

    #pragma unroll 4
    for (int c = 0; c < NC; ++c) {
        const float* p = img + (size_t)c * (ND * NH * NW);
        float v = p[o00 + x0] * w000 + p[o00 + x1] * w001
                + p[o01 + x0] * w010 + p[o01 + x1] * w011
                + p[o10 + x0] * w100 + p[o10 + x1] * w101
                + p[o11 + x0] * w110 + p[o11 + x1] * w111;
        v = valid ? v : 0.0f;
        // stream output past caches; keep image resident in L2/L3
        __builtin_nontemporal_store(v, op + c * (CD * CH * CW));
    }
}

extern "C" void kernel_launch(void* const* d_in, const int* in_sizes, int n_in,
                              void* d_out, int out_size, void* d_ws, size_t ws_size,
                              hipStream_t stream) {
    const float* image   = (const float*)d_in[0];
    const float* boxes   = (const float*)d_in[1];
    const int*   box_ind = (const int*)d_in[2];
    float*       out     = (float*)d_out;

    const int blocks = NBOX * CD;  // 4096
    CropAndResize3D_89481348645400_kernel<<<blocks, 256, 0, stream>>>(
        image, boxes, box_ind, out);
}

// Round 2
// 138.139 us; speedup vs baseline: 1.2394x; 1.2394x over previous
//
#include <hip/hip_runtime.h>

// Problem constants (from reference setup_inputs)
#define NBOX 256
#define NC   32
#define ND   64
#define NH   64
#define NW   64
#define CD   16
#define CH   16
#define CW   16
#define NXCD 8

__global__ __launch_bounds__(256) void CropAndResize3D_89481348645400_kernel(
    const float* __restrict__ image,   // (N, C, D, H, W)
    const float* __restrict__ boxes,   // (NB, 6) = x1,y1,z1,x2,y2,z2
    const int*   __restrict__ box_ind, // (NB,)
    float*       __restrict__ out)     // (NB, C, CD, CH, CW)
{
    // XCD-aware swizzle: hw blocks round-robin over 8 XCDs; remap so that
    // 512 consecutive LOGICAL blocks (32 boxes x 16 z-slices) stay on one
    // XCD -> adjacent z-slices share a z-plane in that XCD's private L2.
    const int nwg_per_xcd = (NBOX * CD) / NXCD;   // 512
    const int hw  = blockIdx.x;
    const int blk = (hw & (NXCD - 1)) * nwg_per_xcd + (hw >> 3);

    const int b = blk >> 4;           // box index
    const int z = blk & 15;           // crop depth index
    const int t = threadIdx.x;        // 256 threads = 16x16 (y,x)
    const int y = t >> 4;
    const int x = t & 15;

    // boxes layout: [x1, y1, z1, x2, y2, z2]
    const float bx1 = boxes[b * 6 + 0];
    const float by1 = boxes[b * 6 + 1];
    const float bz1 = boxes[b * 6 + 2];
    const float bx2 = boxes[b * 6 + 3];
    const float by2 = boxes[b * 6 + 4];
    const float bz2 = boxes[b * 6 + 5];
    const int   n   = box_ind[b];

    // coords exactly as reference: lo*(L-1) + i * ((hi-lo)*(L-1)/(c-1))
    const float zstep = (bz2 - bz1) * (float)(ND - 1) / (float)(CD - 1);
    const float ystep = (by2 - by1) * (float)(NH - 1) / (float)(CH - 1);
    const float xstep = (bx2 - bx1) * (float)(NW - 1) / (float)(CW - 1);
    const float zc = bz1 * (float)(ND - 1) + (float)z * zstep;
    const float yc = by1 * (float)(NH - 1) + (float)y * ystep;
    const float xc = bx1 * (float)(NW - 1) + (float)x * xstep;

    const bool valid =
        (zc >= 0.0f) && (zc <= (float)(ND - 1)) &&
        (yc >= 0.0f) && (yc <= (float)(NH - 1)) &&
        (xc >= 0.0f) && (xc <= (float)(NW - 1));

    // clamp + split into integer corners and fractions
    const float zq = fminf(fmaxf(zc, 0.0f), (float)(ND - 1));
    const float yq = fminf(fmaxf(yc, 0.0f), (float)(NH - 1));
    const float xq = fminf(fmaxf(xc, 0.0f), (float)(NW - 1));
    const int z0 = (int)floorf(zq);
    const int y0 = (int)floorf(yq);
    const int x0 = (int)floorf(xq);
    const int z1 = min(z0 + 1, ND - 1);
    const int y1 = min(y0 + 1, NH - 1);
    const int x1 = min(x0 + 1, NW - 1);
    const float fz = zq - (float)z0;
    const float fy = yq - (float)y0;
    const float fx = xq - (float)x0;
    const float gz = 1.0f - fz, gy = 1.0f - fy, gx = 1.0f - fx;

    // 8 trilinear weights (channel-invariant)
    const float w000 = gz * gy * gx, w001 = gz * gy * fx;
    const float w010 = gz * fy * gx, w011 = gz * fy * fx;
    const float w100 = fz * gy * gx, w101 = fz * gy * fx;
    const float w110 = fz * fy * gx, w111 = fz * fy * fx;

    // channel-invariant spatial offsets within a (D,H,W) volume
    const int o00 = (z0 * NH + y0) * NW;
    const int o01 = (z0 * NH + y1) * NW;
    const int o10 = (z1 * NH + y0) * NW;
    const int o11 = (z1 * NH + y1) * NW;

    const float* img = image + (size_t)n * (NC * ND * NH * NW);
    float* op = out + (size_t)b * (NC * CD * CH * CW) + (z * CH + y) * CW + x;

    #pragma unroll 8
    for (int c = 0; c < NC; ++c) {
        const float* p = img + (size_t)c * (ND * NH * NW);
        float v = p[o00 + x0] * w000 + p[o00 + x1] * w001
                + p[o01 + x0] * w010 + p[o01 + x1] * w011
                + p[o10 + x0] * w100 + p[o10 + x1] * w101
                + p[o11 + x0] * w110 + p[o11 + x1] * w111;
        v = valid ? v : 0.0f;
        // stream output past caches; keep image resident in L2/L3
        __builtin_nontemporal_store(v, op + c * (CD * CH * CW));
    }
}

extern "C" void kernel_launch(void* const* d_in, const int* in_sizes, int n_in,
                              void* d_out, int out_size, void* d_ws, size_t ws_size,
                              hipStream_t stream) {
    const float* image   = (const float*)d_in[0];
    const float* boxes   = (const float*)d_in[1];
    const int*   box_ind = (const int*)d_in[2];
    float*       out     = (float*)d_out;

    const int blocks = NBOX * CD;  // 4096
    CropAndResize3D_89481348645400_kernel<<<blocks, 256, 0, stream>>>(
        image, boxes, box_ind, out);
}